// Round 10
// baseline (212.105 us; speedup 1.0000x reference)
//
#include <hip/hip_runtime.h>

#define TT 140
#define BB 8192
#define HH 64
#define BT 16   // batch tile per wave (MFMA N)
#define HS 72   // h-array stride in fp16 elems (144 B = 16B-aligned b128 frags)
#define K_TANH 2.88539008178f

typedef _Float16 half8 __attribute__((ext_vector_type(8)));
typedef _Float16 half4 __attribute__((ext_vector_type(4)));
typedef float    f32x4 __attribute__((ext_vector_type(4)));

#define MFMA16(a,b,c) __builtin_amdgcn_mfma_f32_16x16x32_f16(a, b, c, 0, 0, 0)

// tanh from PRE-SCALED argument: tanh(x) = 1 - 2/(2^(K*x)+1); caller supplies
// K*x (K folded into the fp16 weights/biases at load -> saves a mul per unit)
__device__ __forceinline__ float tanh_ps(float as) {
    float e = __builtin_amdgcn_exp2f(as);
    return 1.0f - 2.0f * __builtin_amdgcn_rcpf(e + 1.0f);
}

__device__ __forceinline__ half8 ld_frag(const _Float16* p) {
    return *(const half8*)__builtin_assume_aligned(p, 16);
}

// load 8 f32 weights, scale, convert to fp16
__device__ __forceinline__ half8 cvt_frag16s(const float* p, float s) {
    f32x4 wa = *(const f32x4*)p;
    f32x4 wb = *(const f32x4*)(p + 4);
    half8 h;
    #pragma unroll
    for (int j = 0; j < 8; ++j)
        h[j] = (_Float16)(s * ((j < 4) ? wa[j] : wb[j - 4]));
    return h;
}

// BARRIER-FREE single-wave pipeline. Ledger r2-r9: VALUBusy ~50% invariant to
// occupancy (45/42/50/52% at 1/2/2/4 waves per SIMD) and ILP-2 made it WORSE
// (33%, 137us): with trans-ops costed at quarter-rate, r5's issue is ~690 of
// 1430 cyc/phase == the measured 50% -- the other half is CORRELATED stall
// from 141 barrier-locked phases (LDS drain + cross-wave h0 handoff).
// This kernel deletes the barriers: ONE wave owns one 16-batch tile, both
// layers, private LDS h-state. The h0n write->read round trip is same-wave,
// ordered by compiler lgkmcnt (no barrier), and L1's 16 MFMA + 16 tanh sit
// between the write and the dependent read. 512 fully independent waves.
__global__ __launch_bounds__(64, 1)
void rnn_kernel(const float* __restrict__ x,
                const float* __restrict__ h_state,
                const float* __restrict__ W_ih0,
                const float* __restrict__ W_hh0,
                const float* __restrict__ b_ih0,
                const float* __restrict__ b_hh0,
                const float* __restrict__ W_ih1,
                const float* __restrict__ W_hh1,
                const float* __restrict__ b_ih1,
                const float* __restrict__ b_hh1,
                const float* __restrict__ W_out,
                const float* __restrict__ b_out,
                float* __restrict__ out)
{
    __shared__ __align__(16) _Float16 h0s[BT * HS];   // single buffer: same-wave
    __shared__ __align__(16) _Float16 h1s[BT * HS];   // read-then-write per step
    __shared__ float xs[TT * 17];                     // x staged [t][b]

    const int lane = threadIdx.x;     // 0..63 (one wave per block)
    const int col  = lane & 15;       // MFMA col (batch)
    const int q    = lane >> 4;       // quad
    const int b0   = blockIdx.x * BT;

    // ---- A-fragments (fp16, pre-scaled by K_TANH): all 64 units (g=0..3) ----
    half8 A0[4][2], AI[4][2], AH[4][2];
    #pragma unroll
    for (int g = 0; g < 4; ++g)
    #pragma unroll
    for (int kt = 0; kt < 2; ++kt) {
        const int off = (16 * g + col) * HH + 32 * kt + 8 * q;
        A0[g][kt] = cvt_frag16s(W_hh0 + off, K_TANH);
        AI[g][kt] = cvt_frag16s(W_ih1 + off, K_TANH);
        AH[g][kt] = cvt_frag16s(W_hh1 + off, K_TANH);
    }
    // scalars per lane: unit j = 16g + 4q + r. e00/e10/e01 pre-scaled; WO not
    // (it multiplies the tanh OUTPUT, which is unscaled).
    float e00[4][4], e10[4][4], e01[4][4], WO[4][4];
    #pragma unroll
    for (int g = 0; g < 4; ++g)
    #pragma unroll
    for (int r = 0; r < 4; ++r) {
        int j = 16 * g + 4 * q + r;
        e00[g][r] = K_TANH * (b_ih0[j] + b_hh0[j]);
        e10[g][r] = K_TANH * W_ih0[j];
        e01[g][r] = K_TANH * (b_ih1[j] + b_hh1[j]);
        WO[g][r]  = W_out[j];
    }
    const float bout = b_out[0];

    // ---- stage x[b0..b0+15][0..139] into LDS [t][b] ----
    for (int i = lane; i < TT * BT; i += 64) {
        int t = i >> 4, b = i & 15;
        xs[t * 17 + b] = x[(size_t)(b0 + b) * TT + t];
    }
    // ---- init hidden state ----
    for (int i = lane; i < BT * HH; i += 64) {
        int b = i >> 6, u = i & 63;
        h0s[b * HS + u] = (_Float16)h_state[(size_t)(b0 + b) * HH + u];
        h1s[b * HS + u] = (_Float16)h_state[(size_t)BB * HH + (size_t)(b0 + b) * HH + u];
    }
    __syncthreads();   // single wave: effectively free; LDS visibility

    // ---- time loop: NO barriers. iter p: L0(p) then L1(p-1). ----
    for (int p = 0; p <= TT; ++p) {
        // h0n(p-1) (written end of prev iter) and h1(p-2) frags -> registers
        half8 H0a = ld_frag(&h0s[col * HS + 8 * q]);
        half8 H0b = ld_frag(&h0s[col * HS + 32 + 8 * q]);
        half8 H1a = ld_frag(&h1s[col * HS + 8 * q]);
        half8 H1b = ld_frag(&h1s[col * HS + 32 + 8 * q]);

        if (p < TT) {
            // layer0 step p (all 64 units): h0n = tanh(Whh0*h0 + b0 + Wih0*x)
            float xt = xs[p * 17 + col];
            #pragma unroll
            for (int g = 0; g < 4; ++g) {
                f32x4 c = {0.f, 0.f, 0.f, 0.f};
                c = MFMA16(A0[g][0], H0a, c);
                c = MFMA16(A0[g][1], H0b, c);
                half4 h4;
                #pragma unroll
                for (int r = 0; r < 4; ++r)
                    h4[r] = (_Float16)tanh_ps(c[r] + e00[g][r] + e10[g][r] * xt);
                *(half4*)(&h0s[col * HS + 16 * g + 4 * q]) = h4;
            }
        }
        if (p >= 1) {
            // layer1 step s=p-1: uses H0 (= h0n(s), in regs) + H1 (= h1(s-1))
            float pr = 0.f;
            #pragma unroll
            for (int g = 0; g < 4; ++g) {
                f32x4 ci = {0.f, 0.f, 0.f, 0.f}, ch = {0.f, 0.f, 0.f, 0.f};
                ci = MFMA16(AI[g][0], H0a, ci);
                ci = MFMA16(AI[g][1], H0b, ci);
                ch = MFMA16(AH[g][0], H1a, ch);
                ch = MFMA16(AH[g][1], H1b, ch);
                f32x4 a = ci + ch;
                half4 h4;
                #pragma unroll
                for (int r = 0; r < 4; ++r) {
                    float hn = tanh_ps(a[r] + e01[g][r]);
                    pr += hn * WO[g][r];
                    h4[r] = (_Float16)hn;
                }
                *(half4*)(&h1s[col * HS + 16 * g + 4 * q]) = h4;
            }
            // full 64-unit projection: each lane summed its 16 units; fold quads
            pr += __shfl_xor(pr, 16, 64);
            pr += __shfl_xor(pr, 32, 64);
            if (lane < 16)
                out[(size_t)(b0 + lane) * TT + (p - 1)] = pr + bout;
        }
    }

    // ---- h_final: [2,B,H] appended after out[B*T] ----
    const size_t OFF = (size_t)BB * TT;
    for (int i = lane; i < BT * HH; i += 64) {
        int b = i >> 6, u = i & 63;
        out[OFF + (size_t)(b0 + b) * HH + u] = (float)h0s[b * HS + u];
        out[OFF + (size_t)BB * HH + (size_t)(b0 + b) * HH + u] = (float)h1s[b * HS + u];
    }
}

extern "C" void kernel_launch(void* const* d_in, const int* in_sizes, int n_in,
                              void* d_out, int out_size, void* d_ws, size_t ws_size,
                              hipStream_t stream) {
    const float* x      = (const float*)d_in[0];
    const float* hst    = (const float*)d_in[1];
    const float* W_ih0  = (const float*)d_in[2];
    const float* W_hh0  = (const float*)d_in[3];
    const float* b_ih0  = (const float*)d_in[4];
    const float* b_hh0  = (const float*)d_in[5];
    const float* W_ih1  = (const float*)d_in[6];
    const float* W_hh1  = (const float*)d_in[7];
    const float* b_ih1  = (const float*)d_in[8];
    const float* b_hh1  = (const float*)d_in[9];
    const float* W_out  = (const float*)d_in[10];
    const float* b_outp = (const float*)d_in[11];
    float* out = (float*)d_out;

    dim3 grid(BB / BT);   // 512 one-wave blocks: fully independent, ~2/CU
    dim3 block(64);
    rnn_kernel<<<grid, block, 0, stream>>>(x, hst, W_ih0, W_hh0, b_ih0, b_hh0,
                                           W_ih1, W_hh1, b_ih1, b_hh1,
                                           W_out, b_outp, out);
}

// Round 11
// 192.963 us; speedup vs baseline: 1.0992x; 1.0992x over previous
//
#include <hip/hip_runtime.h>

#define TT 140
#define BB 8192
#define HH 64
#define BT 16   // batch tile per wave (MFMA N)
#define K_TANH 2.88539008178f

typedef _Float16 half4 __attribute__((ext_vector_type(4)));
typedef float    f32x4 __attribute__((ext_vector_type(4)));

// K=16 f16 MFMA: D/B layout identity (D: col=lane&15,row=4q+r ; B: col=lane&15,
// k=4q+i) lets tanh(D_g) feed the next MFMA's B k-frag kk=g DIRECTLY.
#define MFMA16(a,b,c) __builtin_amdgcn_mfma_f32_16x16x16f16(a, b, c, 0, 0, 0)

// tanh from PRE-SCALED argument (K_TANH folded into weights/biases):
// tanh(x) = 1 - 2/(2^(K*x)+1)
__device__ __forceinline__ float tanh_ps(float as) {
    float e = __builtin_amdgcn_exp2f(as);
    return 1.0f - 2.0f * __builtin_amdgcn_rcpf(e + 1.0f);
}

// load 4 consecutive f32, scale, convert fp16
__device__ __forceinline__ half4 ldw4(const float* p, float s) {
    f32x4 w = *(const f32x4*)p;
    half4 h;
    #pragma unroll
    for (int i = 0; i < 4; ++i) h[i] = (_Float16)(s * w[i]);
    return h;
}

// FULLY REGISTER-RESIDENT RECURRENCE. Ledger r2-r10: barriered pipelines lose
// ~50% to LDS-burst/VALU-burst serialization (shared CU LDS unit + lockstep
// barriers); barrier-free r10 lost it to the LDS h round-trip in the serial
// chain. This kernel removes LDS from the recurrence: with 16x16x16 MFMA the
// output D layout == B-operand layout, so tanh(D_g) IS the next step's k-frag
// kk=g. h0/h1 never leave registers. No barriers, no h-LDS, no transpose.
// 512 independent waves (one per 16-batch tile), issue-bound by design.
__global__ __launch_bounds__(64, 1)
void rnn_kernel(const float* __restrict__ x,
                const float* __restrict__ h_state,
                const float* __restrict__ W_ih0,
                const float* __restrict__ W_hh0,
                const float* __restrict__ b_ih0,
                const float* __restrict__ b_hh0,
                const float* __restrict__ W_ih1,
                const float* __restrict__ W_hh1,
                const float* __restrict__ b_ih1,
                const float* __restrict__ b_hh1,
                const float* __restrict__ W_out,
                const float* __restrict__ b_out,
                float* __restrict__ out)
{
    __shared__ float xs[TT * 17];     // x staged [t][b]

    const int lane = threadIdx.x;     // one wave per block
    const int n    = lane & 15;       // MFMA col: batch within tile (also A row)
    const int q    = lane >> 4;       // quad
    const int b0   = blockIdx.x * BT;

    // ---- A-frags [g][kk]: lane holds W[16g + n][16kk + 4q + i], K-prescaled.
    half4 A0[4][4], AI[4][4], AH[4][4];
    #pragma unroll
    for (int g = 0; g < 4; ++g)
    #pragma unroll
    for (int kk = 0; kk < 4; ++kk) {
        const int off = (16 * g + n) * HH + 16 * kk + 4 * q;
        A0[g][kk] = ldw4(W_hh0 + off, K_TANH);
        AI[g][kk] = ldw4(W_ih1 + off, K_TANH);
        AH[g][kk] = ldw4(W_hh1 + off, K_TANH);
    }
    // scalars per lane: unit j = 16g + 4q + r (D-row layout), K-prescaled
    float e00[4][4], e10[4][4], e01[4][4], WO[4][4];
    #pragma unroll
    for (int g = 0; g < 4; ++g)
    #pragma unroll
    for (int r = 0; r < 4; ++r) {
        int j = 16 * g + 4 * q + r;
        e00[g][r] = K_TANH * (b_ih0[j] + b_hh0[j]);
        e10[g][r] = K_TANH * W_ih0[j];
        e01[g][r] = K_TANH * (b_ih1[j] + b_hh1[j]);
        WO[g][r]  = W_out[j];
    }
    const float bout = b_out[0];

    // ---- stage x[b0..b0+15][0..139] into LDS [t][b] ----
    for (int i = lane; i < TT * BT; i += 64) {
        int t = i >> 4, b = i & 15;
        xs[t * 17 + b] = x[(size_t)(b0 + b) * TT + t];
    }
    __syncthreads();

    // ---- init H frags (B-operand layout): H[kk][i] = h[16kk+4q+i][batch n]
    half4 H0[4], H1[4];
    #pragma unroll
    for (int kk = 0; kk < 4; ++kk) {
        H0[kk] = ldw4(h_state + (size_t)(b0 + n) * HH + 16 * kk + 4 * q, 1.0f);
        H1[kk] = ldw4(h_state + (size_t)BB * HH + (size_t)(b0 + n) * HH
                               + 16 * kk + 4 * q, 1.0f);
    }

    float xt = xs[n];   // x[t=0] for batch n

    // ---- time loop: zero barriers, zero LDS for h ----
    for (int t = 0; t < TT; ++t) {
        float xn = (t + 1 < TT) ? xs[(t + 1) * 17 + n] : 0.f;   // prefetch
        // L0: d[g] = Whh0_g . h0 + K*(bias0 + Wih0*x)
        f32x4 d[4];
        #pragma unroll
        for (int g = 0; g < 4; ++g) {
            f32x4 c;
            #pragma unroll
            for (int r = 0; r < 4; ++r) c[r] = e00[g][r] + e10[g][r] * xt;
            #pragma unroll
            for (int kk = 0; kk < 4; ++kk) c = MFMA16(A0[g][kk], H0[kk], c);
            d[g] = c;
        }
        // L1 part 1: hh on OLD h1 (independent of L0 -> overlaps L0 tanh)
        f32x4 e[4];
        #pragma unroll
        for (int g = 0; g < 4; ++g) {
            f32x4 c;
            #pragma unroll
            for (int r = 0; r < 4; ++r) c[r] = e01[g][r];
            #pragma unroll
            for (int kk = 0; kk < 4; ++kk) c = MFMA16(AH[g][kk], H1[kk], c);
            e[g] = c;
        }
        // L0 tanh: new h0 frags (D_g -> B-frag kk=g, in place)
        #pragma unroll
        for (int g = 0; g < 4; ++g) {
            half4 h;
            #pragma unroll
            for (int r = 0; r < 4; ++r) h[r] = (_Float16)tanh_ps(d[g][r]);
            H0[g] = h;
        }
        // L1 part 2: ih on NEW h0
        #pragma unroll
        for (int g = 0; g < 4; ++g) {
            f32x4 c = e[g];
            #pragma unroll
            for (int kk = 0; kk < 4; ++kk) c = MFMA16(AI[g][kk], H0[kk], c);
            e[g] = c;
        }
        // L1 tanh + projection: new h1 frags + y
        float pr = 0.f;
        #pragma unroll
        for (int g = 0; g < 4; ++g) {
            half4 h;
            #pragma unroll
            for (int r = 0; r < 4; ++r) {
                float hn = tanh_ps(e[g][r]);
                pr += hn * WO[g][r];
                h[r] = (_Float16)hn;
            }
            H1[g] = h;
        }
        pr += __shfl_xor(pr, 16, 64);
        pr += __shfl_xor(pr, 32, 64);
        if (lane < 16) out[(size_t)(b0 + n) * TT + t] = pr + bout;
        xt = xn;
    }

    // ---- h_final: [2,B,H] appended after out[B*T] ----
    const size_t OFF = (size_t)BB * TT;
    #pragma unroll
    for (int kk = 0; kk < 4; ++kk) {
        f32x4 v0, v1;
        #pragma unroll
        for (int i = 0; i < 4; ++i) {
            v0[i] = (float)H0[kk][i];
            v1[i] = (float)H1[kk][i];
        }
        *(f32x4*)(out + OFF + (size_t)(b0 + n) * HH + 16 * kk + 4 * q) = v0;
        *(f32x4*)(out + OFF + (size_t)BB * HH + (size_t)(b0 + n) * HH
                           + 16 * kk + 4 * q) = v1;
    }
}

extern "C" void kernel_launch(void* const* d_in, const int* in_sizes, int n_in,
                              void* d_out, int out_size, void* d_ws, size_t ws_size,
                              hipStream_t stream) {
    const float* x      = (const float*)d_in[0];
    const float* hst    = (const float*)d_in[1];
    const float* W_ih0  = (const float*)d_in[2];
    const float* W_hh0  = (const float*)d_in[3];
    const float* b_ih0  = (const float*)d_in[4];
    const float* b_hh0  = (const float*)d_in[5];
    const float* W_ih1  = (const float*)d_in[6];
    const float* W_hh1  = (const float*)d_in[7];
    const float* b_ih1  = (const float*)d_in[8];
    const float* b_hh1  = (const float*)d_in[9];
    const float* W_out  = (const float*)d_in[10];
    const float* b_outp = (const float*)d_in[11];
    float* out = (float*)d_out;

    dim3 grid(BB / BT);   // 512 independent one-wave blocks
    dim3 block(64);
    rnn_kernel<<<grid, block, 0, stream>>>(x, hst, W_ih0, W_hh0, b_ih0, b_hh0,
                                           W_ih1, W_hh1, b_ih1, b_hh1,
                                           W_out, b_outp, out);
}

// Round 12
// 166.360 us; speedup vs baseline: 1.2750x; 1.1599x over previous
//
#include <hip/hip_runtime.h>

#define TT 140
#define BB 8192
#define HH 64
#define BT 16   // batch tile per block (MFMA N)
#define K_TANH 2.88539008178f

typedef _Float16 half4 __attribute__((ext_vector_type(4)));
typedef float    f32x4 __attribute__((ext_vector_type(4)));

// K=16 f16 MFMA: D/B layout identity (D: col=lane&15,row=4q+r ; B: col=lane&15,
// k=4q+i) lets tanh(D_g) feed the next MFMA's B k-frag kk=g DIRECTLY.
#define MFMA16(a,b,c) __builtin_amdgcn_mfma_f32_16x16x16f16(a, b, c, 0, 0, 0)

// tanh from PRE-SCALED argument (K_TANH folded into weights/biases)
__device__ __forceinline__ float tanh_ps(float as) {
    float e = __builtin_amdgcn_exp2f(as);
    return 1.0f - 2.0f * __builtin_amdgcn_rcpf(e + 1.0f);
}

__device__ __forceinline__ half4 ldw4(const float* p, float s) {
    f32x4 w = *(const f32x4*)p;
    half4 h;
    #pragma unroll
    for (int i = 0; i < 4; ++i) h[i] = (_Float16)(s * w[i]);
    return h;
}

// WAVE-SPECIALIZED register-resident pipeline. r11 (1 wave owns a whole tile,
// zero LDS in the recurrence) proved the mechanism (bank conflicts 3.5M->35K)
// but used only 2 of 4 SIMDs at 1 wave each: 950 cyc issue vs 2177 wall.
// Per-wave issue is independent of batch count, so the ONLY way to engage all
// 4 SIMDs is splitting one tile's work across two specialized waves:
//   wave A: L0 recurrence (hh0 MFMA+tanh, h0 in regs via D->B identity)
//           + L1's input-side matmul ei = Wih1 . h0n   (~32 MFMA + 16 tanh)
//   wave B: L1 recurrence (hh1 MFMA + ei + tanh, h1 in regs) + projection
//           (~16 MFMA + 16 tanh + proj), pipelined ONE STEP BEHIND A.
// Only the f32 ei partials cross waves (per-lane pass-through, D-layouts
// match, no transform), double-buffered; one barrier per step.
// 512 blocks x 2 waves = 1024 waves = 1 per SIMD on ALL SIMDs.
__global__ __launch_bounds__(128, 1)
void rnn_kernel(const float* __restrict__ x,
                const float* __restrict__ h_state,
                const float* __restrict__ W_ih0,
                const float* __restrict__ W_hh0,
                const float* __restrict__ b_ih0,
                const float* __restrict__ b_hh0,
                const float* __restrict__ W_ih1,
                const float* __restrict__ W_hh1,
                const float* __restrict__ b_ih1,
                const float* __restrict__ b_hh1,
                const float* __restrict__ W_out,
                const float* __restrict__ b_out,
                float* __restrict__ out)
{
    __shared__ float xs[TT * 17];          // x staged [t][b]
    __shared__ f32x4 ei[2][4][64];         // ih1 partials [buf][g][lane], 8 KB

    const int tid  = threadIdx.x;
    const int wid  = tid >> 6;        // 0 = wave A (L0+ih1), 1 = wave B (L1+proj)
    const int lane = tid & 63;
    const int n    = lane & 15;       // MFMA col: batch within tile
    const int q    = lane >> 4;       // quad
    const int b0   = blockIdx.x * BT;

    // ---- per-role constants (loaded in branch; union regalloc is fine at
    //      1 wave/SIMD where up to 512 VGPRs are available) ----
    half4 A0[4][4], AI[4][4], AH[4][4];
    float e00[4][4], e10[4][4], e01[4][4], WO[4][4];
    half4 H0[4], H1[4];
    float bout = 0.f;
    if (wid == 0) {
        #pragma unroll
        for (int g = 0; g < 4; ++g)
        #pragma unroll
        for (int kk = 0; kk < 4; ++kk) {
            const int off = (16 * g + n) * HH + 16 * kk + 4 * q;
            A0[g][kk] = ldw4(W_hh0 + off, K_TANH);
            AI[g][kk] = ldw4(W_ih1 + off, K_TANH);
        }
        #pragma unroll
        for (int g = 0; g < 4; ++g)
        #pragma unroll
        for (int r = 0; r < 4; ++r) {
            int j = 16 * g + 4 * q + r;
            e00[g][r] = K_TANH * (b_ih0[j] + b_hh0[j]);
            e10[g][r] = K_TANH * W_ih0[j];
        }
        #pragma unroll
        for (int kk = 0; kk < 4; ++kk)
            H0[kk] = ldw4(h_state + (size_t)(b0 + n) * HH + 16 * kk + 4 * q, 1.0f);
    } else {
        #pragma unroll
        for (int g = 0; g < 4; ++g)
        #pragma unroll
        for (int kk = 0; kk < 4; ++kk) {
            const int off = (16 * g + n) * HH + 16 * kk + 4 * q;
            AH[g][kk] = ldw4(W_hh1 + off, K_TANH);
        }
        #pragma unroll
        for (int g = 0; g < 4; ++g)
        #pragma unroll
        for (int r = 0; r < 4; ++r) {
            int j = 16 * g + 4 * q + r;
            e01[g][r] = K_TANH * (b_ih1[j] + b_hh1[j]);
            WO[g][r]  = W_out[j];
        }
        #pragma unroll
        for (int kk = 0; kk < 4; ++kk)
            H1[kk] = ldw4(h_state + (size_t)BB * HH + (size_t)(b0 + n) * HH
                                   + 16 * kk + 4 * q, 1.0f);
        bout = b_out[0];
    }

    // ---- stage x[b0..b0+15][0..139] into LDS [t][b] (128 threads) ----
    for (int i = tid; i < TT * BT; i += 128) {
        int t = i >> 4, b = i & 15;
        xs[t * 17 + b] = x[(size_t)(b0 + b) * TT + t];
    }
    __syncthreads();

    // ---- pipelined loop: iter p: A does step p, B does step p-1 ----
    for (int p = 0; p <= TT; ++p) {
        if (wid == 0) {
            if (p < TT) {
                float xt = xs[p * 17 + n];
                // L0: d0 = Whh0.H0 + K*(bias0 + Wih0*x)
                f32x4 d[4];
                #pragma unroll
                for (int g = 0; g < 4; ++g) {
                    f32x4 c;
                    #pragma unroll
                    for (int r = 0; r < 4; ++r) c[r] = e00[g][r] + e10[g][r] * xt;
                    #pragma unroll
                    for (int kk = 0; kk < 4; ++kk) c = MFMA16(A0[g][kk], H0[kk], c);
                    d[g] = c;
                }
                // tanh -> new H0 frags (D_g is next B-frag kk=g)
                #pragma unroll
                for (int g = 0; g < 4; ++g) {
                    half4 h;
                    #pragma unroll
                    for (int r = 0; r < 4; ++r) h[r] = (_Float16)tanh_ps(d[g][r]);
                    H0[g] = h;
                }
                // ih1 partial for wave B: ei = Wih1 . h0n (K-prescaled in AI)
                #pragma unroll
                for (int g = 0; g < 4; ++g) {
                    f32x4 c = {0.f, 0.f, 0.f, 0.f};
                    #pragma unroll
                    for (int kk = 0; kk < 4; ++kk) c = MFMA16(AI[g][kk], H0[kk], c);
                    ei[p & 1][g][lane] = c;
                }
            }
        } else {
            if (p >= 1) {
                const int s = p - 1;
                // L1: d1 = Whh1.H1 + K*bias1 + ei(s)
                f32x4 d[4];
                #pragma unroll
                for (int g = 0; g < 4; ++g) {
                    f32x4 ep = ei[s & 1][g][lane];
                    f32x4 c;
                    #pragma unroll
                    for (int r = 0; r < 4; ++r) c[r] = e01[g][r] + ep[r];
                    #pragma unroll
                    for (int kk = 0; kk < 4; ++kk) c = MFMA16(AH[g][kk], H1[kk], c);
                    d[g] = c;
                }
                float pr = 0.f;
                #pragma unroll
                for (int g = 0; g < 4; ++g) {
                    half4 h;
                    #pragma unroll
                    for (int r = 0; r < 4; ++r) {
                        float hn = tanh_ps(d[g][r]);
                        pr += hn * WO[g][r];
                        h[r] = (_Float16)hn;
                    }
                    H1[g] = h;
                }
                pr += __shfl_xor(pr, 16, 64);
                pr += __shfl_xor(pr, 32, 64);
                if (lane < 16) out[(size_t)(b0 + n) * TT + s] = pr + bout;
            }
        }
        __syncthreads();
    }

    // ---- h_final: [2,B,H] appended after out[B*T] ----
    const size_t OFF = (size_t)BB * TT;
    if (wid == 0) {
        #pragma unroll
        for (int kk = 0; kk < 4; ++kk) {
            f32x4 v;
            #pragma unroll
            for (int i = 0; i < 4; ++i) v[i] = (float)H0[kk][i];
            *(f32x4*)(out + OFF + (size_t)(b0 + n) * HH + 16 * kk + 4 * q) = v;
        }
    } else {
        #pragma unroll
        for (int kk = 0; kk < 4; ++kk) {
            f32x4 v;
            #pragma unroll
            for (int i = 0; i < 4; ++i) v[i] = (float)H1[kk][i];
            *(f32x4*)(out + OFF + (size_t)BB * HH + (size_t)(b0 + n) * HH
                               + 16 * kk + 4 * q) = v;
        }
    }
}

extern "C" void kernel_launch(void* const* d_in, const int* in_sizes, int n_in,
                              void* d_out, int out_size, void* d_ws, size_t ws_size,
                              hipStream_t stream) {
    const float* x      = (const float*)d_in[0];
    const float* hst    = (const float*)d_in[1];
    const float* W_ih0  = (const float*)d_in[2];
    const float* W_hh0  = (const float*)d_in[3];
    const float* b_ih0  = (const float*)d_in[4];
    const float* b_hh0  = (const float*)d_in[5];
    const float* W_ih1  = (const float*)d_in[6];
    const float* W_hh1  = (const float*)d_in[7];
    const float* b_ih1  = (const float*)d_in[8];
    const float* b_hh1  = (const float*)d_in[9];
    const float* W_out  = (const float*)d_in[10];
    const float* b_outp = (const float*)d_in[11];
    float* out = (float*)d_out;

    dim3 grid(BB / BT);   // 512 blocks x 2 waves = 1024 waves = 1 per SIMD
    dim3 block(128);
    rnn_kernel<<<grid, block, 0, stream>>>(x, hst, W_ih0, W_hh0, b_ih0, b_hh0,
                                           W_ih1, W_hh1, b_ih1, b_hh1,
                                           W_out, b_outp, out);
}